// Round 2
// baseline (5679.957 us; speedup 1.0000x reference)
//
#include <hip/hip_runtime.h>
#include <hip/hip_cooperative_groups.h>
#include <math.h>

namespace cg = cooperative_groups;

namespace {

constexpr int BN = 16;      // batch
constexpr int CN = 64;      // input channels
constexpr int HN = 128;     // hidden
constexpr int GN = 64;      // grid dims
constexpr int KH = 2 * HN;          // 256
constexpr int KTOT = KH + CN;       // 320
constexpr int LDSK = 328;           // padded K stride (fp16 elems) -> 656 B rows

typedef _Float16 half8 __attribute__((ext_vector_type(8)));
typedef float float4v __attribute__((ext_vector_type(4)));

__device__ __forceinline__ float sigmoidf_(float z) {
    return 1.f / (1.f + expf(-z));
}

// ---------------- pre-pass: x [B,C,G,G] fp32 -> xb [G,G,B,C] fp16 -------------
__global__ __launch_bounds__(256) void xconv_kernel(
    const float* __restrict__ x, _Float16* __restrict__ xb)
{
    __shared__ float tile[CN][GN + 1];   // [c][j] for one (b,i)
    const int b = blockIdx.x >> 6;
    const int i = blockIdx.x & 63;
    const int t = threadIdx.x;
    const int tj = t & 63, tc = t >> 6;          // 4 c-rows per iter
    for (int c0 = 0; c0 < CN; c0 += 4) {
        const int c = c0 + tc;
        tile[c][tj] = x[((size_t)(b * CN + c) * GN + i) * GN + tj];
    }
    __syncthreads();
    const int wc = t & 63, wj = t >> 6;          // 4 j per iter
    for (int j0 = 0; j0 < GN; j0 += 4) {
        const int j = j0 + wj;
        xb[((size_t)(i * GN + j) * BN + b) * CN + wc] = (_Float16)tile[wc][j];
    }
}

// ---------------- persistent cooperative sweep kernel ------------------------
// 256 blocks = 8 slices x 32 replicas. Slice s -> (dd = s>>2, ug = s&3):
// dim dd, hidden units [ug*32, ug*32+32), all 4 gates (128 gate rows).
// LDS W layout row n = uu*4 + q  (uu in 0..31, q = gate i/f/g/o).
__global__ __launch_bounds__(256, 1) void grid_lstm_persist(
    const _Float16* __restrict__ xb,   // [G,G,B,C]
    const float* __restrict__ Wih,     // [2,512,64]
    const float* __restrict__ Whh,     // [2,512,256]
    const float* __restrict__ bih,     // [2,512]
    const float* __restrict__ bhh,     // [2,512]
    float* __restrict__ out,           // [B,256,G,G]
    _Float16* __restrict__ hbuf,       // [G,G,B,256]
    float* __restrict__ cbuf)          // [2,G,B,H]
{
    __shared__ __align__(16) _Float16 Wl[128 * LDSK];  // 82 KB
    __shared__ __align__(16) _Float16 Hc[BN * LDSK];   // 10.25 KB
    __shared__ __align__(16) float gb[BN * 136];       // 8.5 KB
    __shared__ float blds[128];

    const int t = threadIdx.x;
    const int s = blockIdx.x & 7;
    const int rep = blockIdx.x >> 3;
    const int dd = s >> 2;
    const int ug = s & 3;

    // --- one-time: stage weight slice (fp32 -> fp16) + bias into LDS ---
    for (int e = t; e < 128 * KTOT; e += 256) {
        const int n = e / KTOT, k = e - n * KTOT;
        const int r = (n & 3) * 128 + ug * 32 + (n >> 2);   // row within [512]
        const float w = (k < KH) ? Whh[((size_t)(dd * 512 + r)) * KH + k]
                                 : Wih[((size_t)(dd * 512 + r)) * CN + (k - KH)];
        Wl[n * LDSK + k] = (_Float16)w;
    }
    if (t < 128) {
        const int r = (t & 3) * 128 + ug * 32 + (t >> 2);
        blds[t] = bih[dd * 512 + r] + bhh[dd * 512 + r];
    }

    const int lane = t & 63;
    const int wv = t >> 6;              // wave 0..3
    const int l15 = lane & 15;
    const int l4 = lane >> 4;
    const int n0 = (2 * wv) * 16 + l15;     // N-tile cols handled by this wave
    const int n1 = (2 * wv + 1) * 16 + l15;

    cg::grid_group grid = cg::this_grid();

    for (int d = 0; d < 2 * GN - 1; ++d) {
        grid.sync();   // previous diagonal's hbuf/cbuf writes visible grid-wide
        const int i0 = (d > GN - 1) ? (d - (GN - 1)) : 0;
        const int i1 = (d < GN - 1) ? d : (GN - 1);
        const int nc = i1 - i0 + 1;
        for (int cc = 0; cc < 2; ++cc) {
            const int cell = rep + cc * 32;
            if (cell >= nc) break;                 // block-uniform
            const int i = i0 + cell, j = d - i;

            __syncthreads();   // Hc free (prev cell's MFMA reads done)
            // --- stage Hcat = [h1(i-1,j) | h2(i,j-1) | x(i,j)] as fp16 ---
            for (int e = t; e < BN * 80; e += 256) {
                const int b = e / 80, c4 = e - b * 80;   // c4: 8B chunk (4 fp16)
                uint2 v = make_uint2(0u, 0u);
                if (c4 < 32) {
                    if (i > 0)
                        v = *(const uint2*)(hbuf + ((size_t)((i - 1) * GN + j)) * (BN * KH)
                                            + b * KH + c4 * 4);
                } else if (c4 < 64) {
                    if (j > 0)
                        v = *(const uint2*)(hbuf + ((size_t)(i * GN + (j - 1))) * (BN * KH)
                                            + b * KH + c4 * 4);
                } else {
                    v = *(const uint2*)(xb + ((size_t)(i * GN + j)) * (BN * CN)
                                        + b * CN + (c4 - 64) * 4);
                }
                *(uint2*)(&Hc[b * LDSK + c4 * 4]) = v;
            }
            __syncthreads();

            // --- gates[16,128] = Hcat[16,320] @ Wslice^T via MFMA ---
            float4v acc0 = {0.f, 0.f, 0.f, 0.f};
            float4v acc1 = {0.f, 0.f, 0.f, 0.f};
            #pragma unroll
            for (int ks = 0; ks < KTOT / 32; ++ks) {
                const half8 a  = *(const half8*)(&Hc[l15 * LDSK + ks * 32 + l4 * 8]);
                const half8 b0 = *(const half8*)(&Wl[n0 * LDSK + ks * 32 + l4 * 8]);
                const half8 b1 = *(const half8*)(&Wl[n1 * LDSK + ks * 32 + l4 * 8]);
                acc0 = __builtin_amdgcn_mfma_f32_16x16x32_f16(a, b0, acc0, 0, 0, 0);
                acc1 = __builtin_amdgcn_mfma_f32_16x16x32_f16(a, b1, acc1, 0, 0, 0);
            }
            // D + bias -> gb[m][n]   (n = uu*4+q so i,f,g,o contiguous per unit)
            #pragma unroll
            for (int rg = 0; rg < 4; ++rg) {
                const int m = l4 * 4 + rg;
                gb[m * 136 + n0] = acc0[rg] + blds[n0];
                gb[m * 136 + n1] = acc1[rg] + blds[n1];
            }
            __syncthreads();

            // --- pointwise LSTM update: 16 b x 32 units ---
            const int line = (dd == 0) ? j : i;
            const bool hasp = (dd == 0) ? (i > 0) : (j > 0);
            for (int e = t; e < BN * 32; e += 256) {
                const int uu = e & 31, b = e >> 5;
                const float4v g4 = *(const float4v*)(&gb[b * 136 + uu * 4]);
                const float gi = sigmoidf_(g4.x);
                const float gf = sigmoidf_(g4.y);
                const float gg = tanhf(g4.z);
                const float go = sigmoidf_(g4.w);
                const int hu = ug * 32 + uu;
                const size_t cidx = ((size_t)(dd * GN + line) * BN + b) * HN + hu;
                const float cp = hasp ? cbuf[cidx] : 0.f;
                const float c = gf * cp + gi * gg;
                cbuf[cidx] = c;
                const float h = go * tanhf(c);
                hbuf[((size_t)(i * GN + j)) * (BN * KH) + b * KH + dd * HN + hu] = (_Float16)h;
                out[(((size_t)b * KH + dd * HN + hu) * GN + i) * GN + j] = h;
            }
        }
    }
}

// ---------------- fallback (round-1 kernel, fp32, launch-per-diagonal) -------
constexpr int KCH = 32;
constexpr int NCH = KTOT / KCH;

__global__ __launch_bounds__(256, 1) void diag_kernel(
    const float* __restrict__ x, const float* __restrict__ Wih,
    const float* __restrict__ Whh, const float* __restrict__ bih,
    const float* __restrict__ bhh, float* __restrict__ out,
    float* __restrict__ cbuf, int d)
{
    __shared__ float HcF[BN][KTOT];
    __shared__ float Wch[KCH][257];
    const int cell = blockIdx.x >> 2;
    const int slice = blockIdx.x & 3;
    const int dd = slice >> 1;
    const int h0 = (slice & 1) * 64;
    const int i0 = (d > GN - 1) ? (d - (GN - 1)) : 0;
    const int i = i0 + cell;
    const int j = d - i;
    const int t = threadIdx.x;
    for (int e = t; e < BN * KTOT; e += 256) {
        const int b = e / KTOT, k = e - b * KTOT;
        float v;
        if (k < HN)      v = (i > 0) ? out[((b * KH + k) * GN + (i - 1)) * GN + j] : 0.f;
        else if (k < KH) v = (j > 0) ? out[((b * KH + k) * GN + i) * GN + (j - 1)] : 0.f;
        else             v = x[((b * CN + (k - KH)) * GN + i) * GN + j];
        HcF[b][k] = v;
    }
    const int h = t & 63, bg = t >> 6;
    const int grow = dd * 4 * HN + bg * HN + h0 + h;
    float acc[4][4];
    #pragma unroll
    for (int qq = 0; qq < 4; ++qq)
        #pragma unroll
        for (int bb = 0; bb < 4; ++bb) acc[qq][bb] = 0.f;
    for (int kb = 0; kb < NCH; ++kb) {
        const int kbase = kb * KCH;
        __syncthreads();
        const float* src = (kbase < KH) ? (Whh + (size_t)grow * KH + kbase)
                                        : (Wih + (size_t)grow * CN + (kbase - KH));
        #pragma unroll
        for (int k4 = 0; k4 < KCH / 4; ++k4) {
            const float4 w = *(const float4*)(src + k4 * 4);
            Wch[k4 * 4 + 0][t] = w.x; Wch[k4 * 4 + 1][t] = w.y;
            Wch[k4 * 4 + 2][t] = w.z; Wch[k4 * 4 + 3][t] = w.w;
        }
        __syncthreads();
        #pragma unroll 8
        for (int kk = 0; kk < KCH; ++kk) {
            const float w0 = Wch[kk][0 * 64 + h], w1 = Wch[kk][1 * 64 + h];
            const float w2 = Wch[kk][2 * 64 + h], w3 = Wch[kk][3 * 64 + h];
            #pragma unroll
            for (int bb = 0; bb < 4; ++bb) {
                const float hv = HcF[bg * 4 + bb][kbase + kk];
                acc[0][bb] = fmaf(w0, hv, acc[0][bb]);
                acc[1][bb] = fmaf(w1, hv, acc[1][bb]);
                acc[2][bb] = fmaf(w2, hv, acc[2][bb]);
                acc[3][bb] = fmaf(w3, hv, acc[3][bb]);
            }
        }
    }
    const int hu = h0 + h;
    float bias[4];
    #pragma unroll
    for (int qq = 0; qq < 4; ++qq) {
        const int gidx = dd * 4 * HN + qq * HN + hu;
        bias[qq] = bih[gidx] + bhh[gidx];
    }
    float* cptr = (dd == 0) ? (cbuf + (size_t)j * BN * HN)
                            : (cbuf + (size_t)GN * BN * HN + (size_t)i * BN * HN);
    const bool has_prev = (dd == 0) ? (i > 0) : (j > 0);
    #pragma unroll
    for (int bb = 0; bb < 4; ++bb) {
        const int b = bg * 4 + bb;
        const float gi = sigmoidf_(acc[0][bb] + bias[0]);
        const float gf = sigmoidf_(acc[1][bb] + bias[1]);
        const float gg = tanhf(acc[2][bb] + bias[2]);
        const float go = sigmoidf_(acc[3][bb] + bias[3]);
        const float cp = has_prev ? cptr[b * HN + hu] : 0.f;
        const float c = gf * cp + gi * gg;
        cptr[b * HN + hu] = c;
        out[((b * KH + dd * HN + hu) * GN + i) * GN + j] = go * tanhf(c);
    }
}

} // anonymous namespace

extern "C" void kernel_launch(void* const* d_in, const int* in_sizes, int n_in,
                              void* d_out, int out_size, void* d_ws, size_t ws_size,
                              hipStream_t stream) {
    const float* x   = (const float*)d_in[0];
    const float* Wih = (const float*)d_in[1];
    const float* Whh = (const float*)d_in[2];
    const float* bih = (const float*)d_in[3];
    const float* bhh = (const float*)d_in[4];
    float* out = (float*)d_out;

    const size_t XB_BYTES = (size_t)GN * GN * BN * CN * 2;        // 8 MB
    const size_t HB_BYTES = (size_t)GN * GN * BN * KH * 2;        // 8 MB
    const size_t CB_BYTES = (size_t)2 * GN * BN * HN * 4;         // 1 MB
    const size_t NEED = XB_BYTES + HB_BYTES + CB_BYTES;           // 17 MB

    if (ws_size >= NEED) {
        _Float16* xbp  = (_Float16*)d_ws;
        _Float16* hbuf = (_Float16*)((char*)d_ws + XB_BYTES);
        float*    cbuf = (float*)((char*)d_ws + XB_BYTES + HB_BYTES);

        hipLaunchKernelGGL(xconv_kernel, dim3(BN * GN), dim3(256), 0, stream, x, xbp);

        void* args[] = { (void*)&xbp, (void*)&Wih, (void*)&Whh, (void*)&bih,
                         (void*)&bhh, (void*)&out, (void*)&hbuf, (void*)&cbuf };
        hipLaunchCooperativeKernel((const void*)grid_lstm_persist,
                                   dim3(256), dim3(256), args, 0, stream);
    } else {
        // fallback: per-diagonal fp32 path (needs 1 MB ws)
        float* cbuf = (float*)d_ws;
        for (int d = 0; d < 2 * GN - 1; ++d) {
            const int i0 = (d > GN - 1) ? (d - (GN - 1)) : 0;
            const int i1 = (d < GN - 1) ? d : (GN - 1);
            const int nc = i1 - i0 + 1;
            hipLaunchKernelGGL(diag_kernel, dim3(nc * 4), dim3(256), 0, stream,
                               x, Wih, Whh, bih, bhh, out, cbuf, d);
        }
    }
}

// Round 3
// 1965.324 us; speedup vs baseline: 2.8901x; 2.8901x over previous
//
#include <hip/hip_runtime.h>
#include <math.h>

namespace {

constexpr int BN = 16;      // batch
constexpr int CN = 64;      // input channels
constexpr int HN = 128;     // hidden
constexpr int GN = 64;      // grid dims
constexpr int KH = 2 * HN;          // 256
constexpr int KTOT = KH + CN;       // 320
constexpr int LDSK = 328;           // padded K stride (fp16 elems)

typedef _Float16 half8 __attribute__((ext_vector_type(8)));
typedef float float4v __attribute__((ext_vector_type(4)));

__device__ __forceinline__ float sigmoidf_(float z) {
    return 1.f / (1.f + expf(-z));
}

// ---------------- pre-pass: x [B,C,G,G] fp32 -> xb [G,G,B,C] fp16 -------------
__global__ __launch_bounds__(256) void xconv_kernel(
    const float* __restrict__ x, _Float16* __restrict__ xb)
{
    __shared__ float tile[CN][GN + 1];   // [c][j] for one (b,i)
    const int b = blockIdx.x >> 6;
    const int i = blockIdx.x & 63;
    const int t = threadIdx.x;
    const int tj = t & 63, tc = t >> 6;
    for (int c0 = 0; c0 < CN; c0 += 4) {
        const int c = c0 + tc;
        tile[c][tj] = x[((size_t)(b * CN + c) * GN + i) * GN + tj];
    }
    __syncthreads();
    const int wc = t & 63, wj = t >> 6;
    for (int j0 = 0; j0 < GN; j0 += 4) {
        const int j = j0 + wj;
        xb[((size_t)(i * GN + j) * BN + b) * CN + wc] = (_Float16)tile[wc][j];
    }
}

// ---------------- post-pass: hbuf [G,G,B,256] fp16 -> out [B,256,G,G] fp32 ----
__global__ __launch_bounds__(256) void out_kernel(
    const _Float16* __restrict__ hbuf, float* __restrict__ out)
{
    const int b = blockIdx.x >> 6;
    const int i = blockIdx.x & 63;
    const int t = threadIdx.x;          // channel 0..255
    float* op = out + ((size_t)(b * KH + t)) * (GN * GN) + (size_t)i * GN;
    const _Float16* hp = hbuf + ((size_t)i * GN * BN + b) * KH + t;
    #pragma unroll 4
    for (int j = 0; j < GN; ++j)
        op[j] = (float)hp[(size_t)j * (BN * KH)];
}

// ---------------- persistent dataflow sweep kernel ---------------------------
// 256 blocks = 8 slices x 32 replicas. Slice s -> (dd = s>>2, ug = s&3):
// dim dd, hidden units [ug*32, ug*32+32), all 4 gates (128 gate rows).
// Point-to-point sync: flags[i][j] counts completed slices (8 = cell done).
__global__ __launch_bounds__(256, 1) void grid_lstm_persist(
    const _Float16* __restrict__ xb,   // [G,G,B,C]
    const float* __restrict__ Wih,     // [2,512,64]
    const float* __restrict__ Whh,     // [2,512,256]
    const float* __restrict__ bih,     // [2,512]
    const float* __restrict__ bhh,     // [2,512]
    _Float16* __restrict__ hbuf,       // [G,G,B,256]
    float* __restrict__ cbuf,          // [2,G,B,H]
    int* __restrict__ flags)           // [G,G]
{
    __shared__ __align__(16) _Float16 Wl[128 * LDSK];  // 82 KB
    __shared__ __align__(16) _Float16 Hc[BN * LDSK];   // 10.25 KB
    __shared__ __align__(16) float gb[BN * 136];       // 8.5 KB
    __shared__ float blds[128];

    const int t = threadIdx.x;
    const int s = blockIdx.x & 7;
    const int rep = blockIdx.x >> 3;
    const int dd = s >> 2;
    const int ug = s & 3;

    // --- one-time: stage weight slice (fp32 -> fp16) + bias into LDS ---
    for (int e = t; e < 128 * KTOT; e += 256) {
        const int n = e / KTOT, k = e - n * KTOT;
        const int r = (n & 3) * 128 + ug * 32 + (n >> 2);   // row within [512]
        const float w = (k < KH) ? Whh[((size_t)(dd * 512 + r)) * KH + k]
                                 : Wih[((size_t)(dd * 512 + r)) * CN + (k - KH)];
        Wl[n * LDSK + k] = (_Float16)w;
    }
    if (t < 128) {
        const int r = (t & 3) * 128 + ug * 32 + (t >> 2);
        blds[t] = bih[dd * 512 + r] + bhh[dd * 512 + r];
    }
    __syncthreads();

    const int lane = t & 63;
    const int wv = t >> 6;
    const int l15 = lane & 15;
    const int l4 = lane >> 4;
    const int n0 = (2 * wv) * 16 + l15;
    const int n1 = (2 * wv + 1) * 16 + l15;

    for (int d = 0; d < 2 * GN - 1; ++d) {
        const int i0 = (d > GN - 1) ? (d - (GN - 1)) : 0;
        const int i1 = (d < GN - 1) ? d : (GN - 1);
        const int nc = i1 - i0 + 1;
        for (int cc = 0; cc < 2; ++cc) {
            const int cell = rep + cc * 32;
            if (cell >= nc) break;                 // block-uniform
            const int i = i0 + cell, j = d - i;

            // --- wait for the two producer cells (point-to-point) ---
            if (t == 0 && i > 0) {
                const int* fp = flags + (i - 1) * GN + j;
                int it = 0;
                while (__hip_atomic_load(fp, __ATOMIC_RELAXED,
                                         __HIP_MEMORY_SCOPE_AGENT) < 8) {
                    __builtin_amdgcn_s_sleep(1);
                    if (++it > (1 << 24)) break;   // failsafe, never expected
                }
                (void)__hip_atomic_load(fp, __ATOMIC_ACQUIRE,
                                        __HIP_MEMORY_SCOPE_AGENT);
            }
            if (t == 64 && j > 0) {
                const int* fp = flags + i * GN + (j - 1);
                int it = 0;
                while (__hip_atomic_load(fp, __ATOMIC_RELAXED,
                                         __HIP_MEMORY_SCOPE_AGENT) < 8) {
                    __builtin_amdgcn_s_sleep(1);
                    if (++it > (1 << 24)) break;
                }
                (void)__hip_atomic_load(fp, __ATOMIC_ACQUIRE,
                                        __HIP_MEMORY_SCOPE_AGENT);
            }
            __syncthreads();

            // --- stage Hcat = [h1(i-1,j) | h2(i,j-1) | x(i,j)] as fp16 ---
            for (int e = t; e < BN * 80; e += 256) {
                const int b = e / 80, c4 = e - b * 80;   // c4: 8B chunk (4 fp16)
                uint2 v = make_uint2(0u, 0u);
                if (c4 < 32) {
                    if (i > 0)
                        v = *(const uint2*)(hbuf + ((size_t)((i - 1) * GN + j)) * (BN * KH)
                                            + b * KH + c4 * 4);
                } else if (c4 < 64) {
                    if (j > 0)
                        v = *(const uint2*)(hbuf + ((size_t)(i * GN + (j - 1))) * (BN * KH)
                                            + b * KH + c4 * 4);
                } else {
                    v = *(const uint2*)(xb + ((size_t)(i * GN + j)) * (BN * CN)
                                        + b * CN + (c4 - 64) * 4);
                }
                *(uint2*)(&Hc[b * LDSK + c4 * 4]) = v;
            }
            __syncthreads();

            // --- gates[16,128] = Hcat[16,320] @ Wslice^T via MFMA ---
            float4v acc0 = {0.f, 0.f, 0.f, 0.f};
            float4v acc1 = {0.f, 0.f, 0.f, 0.f};
            #pragma unroll
            for (int ks = 0; ks < KTOT / 32; ++ks) {
                const half8 a  = *(const half8*)(&Hc[l15 * LDSK + ks * 32 + l4 * 8]);
                const half8 b0 = *(const half8*)(&Wl[n0 * LDSK + ks * 32 + l4 * 8]);
                const half8 b1 = *(const half8*)(&Wl[n1 * LDSK + ks * 32 + l4 * 8]);
                acc0 = __builtin_amdgcn_mfma_f32_16x16x32_f16(a, b0, acc0, 0, 0, 0);
                acc1 = __builtin_amdgcn_mfma_f32_16x16x32_f16(a, b1, acc1, 0, 0, 0);
            }
            #pragma unroll
            for (int rg = 0; rg < 4; ++rg) {
                const int m = l4 * 4 + rg;
                gb[m * 136 + n0] = acc0[rg] + blds[n0];
                gb[m * 136 + n1] = acc1[rg] + blds[n1];
            }
            __syncthreads();

            // --- pointwise LSTM update: 16 b x 32 units ---
            const int line = (dd == 0) ? j : i;
            const bool hasp = (dd == 0) ? (i > 0) : (j > 0);
            for (int e = t; e < BN * 32; e += 256) {
                const int uu = e & 31, b = e >> 5;
                const float4v g4 = *(const float4v*)(&gb[b * 136 + uu * 4]);
                const float gi = sigmoidf_(g4.x);
                const float gf = sigmoidf_(g4.y);
                const float gg = tanhf(g4.z);
                const float go = sigmoidf_(g4.w);
                const int hu = ug * 32 + uu;
                const size_t cidx = ((size_t)(dd * GN + line) * BN + b) * HN + hu;
                const float cp = hasp ? cbuf[cidx] : 0.f;
                const float c = gf * cp + gi * gg;
                cbuf[cidx] = c;
                hbuf[((size_t)(i * GN + j)) * (BN * KH) + b * KH + dd * HN + hu] =
                    (_Float16)(go * tanhf(c));
            }
            __syncthreads();   // drain all stores (compiler emits vmcnt(0))

            // --- publish: release-increment this cell's flag ---
            if (t == 0)
                __hip_atomic_fetch_add(flags + i * GN + j, 1,
                                       __ATOMIC_RELEASE, __HIP_MEMORY_SCOPE_AGENT);
        }
    }
}

// ---------------- fallback (round-1 kernel, fp32, launch-per-diagonal) -------
constexpr int KCH = 32;
constexpr int NCH = KTOT / KCH;

__global__ __launch_bounds__(256, 1) void diag_kernel(
    const float* __restrict__ x, const float* __restrict__ Wih,
    const float* __restrict__ Whh, const float* __restrict__ bih,
    const float* __restrict__ bhh, float* __restrict__ out,
    float* __restrict__ cbuf, int d)
{
    __shared__ float HcF[BN][KTOT];
    __shared__ float Wch[KCH][257];
    const int cell = blockIdx.x >> 2;
    const int slice = blockIdx.x & 3;
    const int dd = slice >> 1;
    const int h0 = (slice & 1) * 64;
    const int i0 = (d > GN - 1) ? (d - (GN - 1)) : 0;
    const int i = i0 + cell;
    const int j = d - i;
    const int t = threadIdx.x;
    for (int e = t; e < BN * KTOT; e += 256) {
        const int b = e / KTOT, k = e - b * KTOT;
        float v;
        if (k < HN)      v = (i > 0) ? out[((b * KH + k) * GN + (i - 1)) * GN + j] : 0.f;
        else if (k < KH) v = (j > 0) ? out[((b * KH + k) * GN + i) * GN + (j - 1)] : 0.f;
        else             v = x[((b * CN + (k - KH)) * GN + i) * GN + j];
        HcF[b][k] = v;
    }
    const int h = t & 63, bg = t >> 6;
    const int grow = dd * 4 * HN + bg * HN + h0 + h;
    float acc[4][4];
    #pragma unroll
    for (int qq = 0; qq < 4; ++qq)
        #pragma unroll
        for (int bb = 0; bb < 4; ++bb) acc[qq][bb] = 0.f;
    for (int kb = 0; kb < NCH; ++kb) {
        const int kbase = kb * KCH;
        __syncthreads();
        const float* src = (kbase < KH) ? (Whh + (size_t)grow * KH + kbase)
                                        : (Wih + (size_t)grow * CN + (kbase - KH));
        #pragma unroll
        for (int k4 = 0; k4 < KCH / 4; ++k4) {
            const float4 w = *(const float4*)(src + k4 * 4);
            Wch[k4 * 4 + 0][t] = w.x; Wch[k4 * 4 + 1][t] = w.y;
            Wch[k4 * 4 + 2][t] = w.z; Wch[k4 * 4 + 3][t] = w.w;
        }
        __syncthreads();
        #pragma unroll 8
        for (int kk = 0; kk < KCH; ++kk) {
            const float w0 = Wch[kk][0 * 64 + h], w1 = Wch[kk][1 * 64 + h];
            const float w2 = Wch[kk][2 * 64 + h], w3 = Wch[kk][3 * 64 + h];
            #pragma unroll
            for (int bb = 0; bb < 4; ++bb) {
                const float hv = HcF[bg * 4 + bb][kbase + kk];
                acc[0][bb] = fmaf(w0, hv, acc[0][bb]);
                acc[1][bb] = fmaf(w1, hv, acc[1][bb]);
                acc[2][bb] = fmaf(w2, hv, acc[2][bb]);
                acc[3][bb] = fmaf(w3, hv, acc[3][bb]);
            }
        }
    }
    const int hu = h0 + h;
    float bias[4];
    #pragma unroll
    for (int qq = 0; qq < 4; ++qq) {
        const int gidx = dd * 4 * HN + qq * HN + hu;
        bias[qq] = bih[gidx] + bhh[gidx];
    }
    float* cptr = (dd == 0) ? (cbuf + (size_t)j * BN * HN)
                            : (cbuf + (size_t)GN * BN * HN + (size_t)i * BN * HN);
    const bool has_prev = (dd == 0) ? (i > 0) : (j > 0);
    #pragma unroll
    for (int bb = 0; bb < 4; ++bb) {
        const int b = bg * 4 + bb;
        const float gi = sigmoidf_(acc[0][bb] + bias[0]);
        const float gf = sigmoidf_(acc[1][bb] + bias[1]);
        const float gg = tanhf(acc[2][bb] + bias[2]);
        const float go = sigmoidf_(acc[3][bb] + bias[3]);
        const float cp = has_prev ? cptr[b * HN + hu] : 0.f;
        const float c = gf * cp + gi * gg;
        cptr[b * HN + hu] = c;
        out[((b * KH + dd * HN + hu) * GN + i) * GN + j] = go * tanhf(c);
    }
}

} // anonymous namespace

extern "C" void kernel_launch(void* const* d_in, const int* in_sizes, int n_in,
                              void* d_out, int out_size, void* d_ws, size_t ws_size,
                              hipStream_t stream) {
    const float* x   = (const float*)d_in[0];
    const float* Wih = (const float*)d_in[1];
    const float* Whh = (const float*)d_in[2];
    const float* bih = (const float*)d_in[3];
    const float* bhh = (const float*)d_in[4];
    float* out = (float*)d_out;

    const size_t XB_BYTES = (size_t)GN * GN * BN * CN * 2;        // 8 MB
    const size_t HB_BYTES = (size_t)GN * GN * BN * KH * 2;        // 8 MB
    const size_t CB_BYTES = (size_t)2 * GN * BN * HN * 4;         // 1 MB
    const size_t FL_BYTES = (size_t)GN * GN * 4;                  // 16 KB
    const size_t NEED = XB_BYTES + HB_BYTES + CB_BYTES + FL_BYTES;

    if (ws_size >= NEED) {
        _Float16* xbp  = (_Float16*)d_ws;
        _Float16* hbuf = (_Float16*)((char*)d_ws + XB_BYTES);
        float*    cbuf = (float*)((char*)d_ws + XB_BYTES + HB_BYTES);
        int*      flags = (int*)((char*)d_ws + XB_BYTES + HB_BYTES + CB_BYTES);

        hipMemsetAsync(flags, 0, FL_BYTES, stream);
        hipLaunchKernelGGL(xconv_kernel, dim3(BN * GN), dim3(256), 0, stream, x, xbp);

        void* args[] = { (void*)&xbp, (void*)&Wih, (void*)&Whh, (void*)&bih,
                         (void*)&bhh, (void*)&hbuf, (void*)&cbuf, (void*)&flags };
        hipLaunchCooperativeKernel((const void*)grid_lstm_persist,
                                   dim3(256), dim3(256), args, 0, stream);

        hipLaunchKernelGGL(out_kernel, dim3(BN * GN), dim3(256), 0, stream, hbuf, out);
    } else {
        float* cbuf = (float*)d_ws;
        for (int d = 0; d < 2 * GN - 1; ++d) {
            const int i0 = (d > GN - 1) ? (d - (GN - 1)) : 0;
            const int i1 = (d < GN - 1) ? d : (GN - 1);
            const int nc = i1 - i0 + 1;
            hipLaunchKernelGGL(diag_kernel, dim3(nc * 4), dim3(256), 0, stream,
                               x, Wih, Whh, bih, bhh, out, cbuf, d);
        }
    }
}

// Round 7
// 1300.635 us; speedup vs baseline: 4.3671x; 1.5111x over previous
//
#include <hip/hip_runtime.h>
#include <math.h>

namespace {

constexpr int BN = 16;      // batch
constexpr int CN = 64;      // input channels
constexpr int HN = 128;     // hidden
constexpr int GN = 64;      // grid dims
constexpr int KH = 2 * HN;          // 256
constexpr int KTOT = KH + CN;       // 320
constexpr int LDSK = 328;           // padded K stride (fp16 elems)

typedef _Float16 half8 __attribute__((ext_vector_type(8)));
typedef float float4v __attribute__((ext_vector_type(4)));
typedef unsigned long long u64;

__device__ __forceinline__ float sigmoidf_(float z) {
    return 1.f / (1.f + expf(-z));
}

// ---------------- pre-pass: x [B,C,G,G] fp32 -> xb [G,G,B,C] fp16 -------------
__global__ __launch_bounds__(256) void xconv_kernel(
    const float* __restrict__ x, _Float16* __restrict__ xb)
{
    __shared__ float tile[CN][GN + 1];   // [c][j] for one (b,i)
    const int b = blockIdx.x >> 6;
    const int i = blockIdx.x & 63;
    const int t = threadIdx.x;
    const int tj = t & 63, tc = t >> 6;
    for (int c0 = 0; c0 < CN; c0 += 4) {
        const int c = c0 + tc;
        tile[c][tj] = x[((size_t)(b * CN + c) * GN + i) * GN + tj];
    }
    __syncthreads();
    const int wc = t & 63, wj = t >> 6;
    for (int j0 = 0; j0 < GN; j0 += 4) {
        const int j = j0 + wj;
        xb[((size_t)(i * GN + j) * BN + b) * CN + wc] = (_Float16)tile[wc][j];
    }
}

// ---------------- post-pass: hbuf [G,G,B,256] fp16 -> out [B,256,G,G] fp32 ----
__global__ __launch_bounds__(256) void out_kernel(
    const _Float16* __restrict__ hbuf, float* __restrict__ out)
{
    const int b = blockIdx.x >> 6;
    const int i = blockIdx.x & 63;
    const int t = threadIdx.x;          // channel 0..255
    float* op = out + ((size_t)(b * KH + t)) * (GN * GN) + (size_t)i * GN;
    const _Float16* hp = hbuf + ((size_t)i * GN * BN + b) * KH + t;
    #pragma unroll 4
    for (int j = 0; j < GN; ++j)
        op[j] = (float)hp[(size_t)j * (BN * KH)];
}

// ---------------- persistent dataflow sweep kernel ---------------------------
// ROUND-7: byte-level identical to the round-3 PASSING kernel (8 slices/cell,
// LDS weights, Hc staging, gb epilogue, cc loop) EXCEPT the cross-block
// communication protocol: all communicated data (hbuf, cbuf) moves via
// relaxed AGENT-scope atomics (sc0sc1 coherent accesses straight to the
// coherence point); flags are relaxed too. No buffer_wbl2 / buffer_inv on
// the critical path. Producer ordering: coherent stores -> per-wave
// vmcnt(0) -> barrier -> flag add. Consumer: relaxed poll -> barrier ->
// coherent loads.
__global__ __launch_bounds__(256, 1) void grid_lstm_persist(
    const _Float16* __restrict__ xb,   // [G,G,B,C]
    const float* __restrict__ Wih,     // [2,512,64]
    const float* __restrict__ Whh,     // [2,512,256]
    const float* __restrict__ bih,     // [2,512]
    const float* __restrict__ bhh,     // [2,512]
    _Float16* __restrict__ hbuf,       // [G,G,B,256]
    float* __restrict__ cbuf,          // [2,G,B,H]
    int* __restrict__ flags)           // [G,G], target 8
{
    __shared__ __align__(16) _Float16 Wl[128 * LDSK];  // 82 KB
    __shared__ __align__(16) _Float16 Hc[BN * LDSK];   // 10.25 KB
    __shared__ __align__(16) float gb[BN * 136];       // 8.5 KB
    __shared__ float blds[128];

    const int t = threadIdx.x;
    const int s = blockIdx.x & 7;
    const int rep = blockIdx.x >> 3;
    const int dd = s >> 2;
    const int ug = s & 3;

    // --- one-time: stage weight slice (fp32 -> fp16) + bias into LDS ---
    for (int e = t; e < 128 * KTOT; e += 256) {
        const int n = e / KTOT, k = e - n * KTOT;
        const int r = (n & 3) * 128 + ug * 32 + (n >> 2);   // row within [512]
        const float w = (k < KH) ? Whh[((size_t)(dd * 512 + r)) * KH + k]
                                 : Wih[((size_t)(dd * 512 + r)) * CN + (k - KH)];
        Wl[n * LDSK + k] = (_Float16)w;
    }
    if (t < 128) {
        const int r = (t & 3) * 128 + ug * 32 + (t >> 2);
        blds[t] = bih[dd * 512 + r] + bhh[dd * 512 + r];
    }
    __syncthreads();

    const int lane = t & 63;
    const int wv = t >> 6;
    const int l15 = lane & 15;
    const int l4 = lane >> 4;
    const int n0 = (2 * wv) * 16 + l15;
    const int n1 = (2 * wv + 1) * 16 + l15;

    for (int d = 0; d < 2 * GN - 1; ++d) {
        const int i0 = (d > GN - 1) ? (d - (GN - 1)) : 0;
        const int i1 = (d < GN - 1) ? d : (GN - 1);
        const int nc = i1 - i0 + 1;
        for (int cc = 0; cc < 2; ++cc) {
            const int cell = rep + cc * 32;
            if (cell >= nc) break;                 // block-uniform
            const int i = i0 + cell, j = d - i;
            const int cellidx = i * GN + j;

            // --- wait for producers: relaxed polls (coherent-point reads) ---
            if (t == 0 && i > 0) {
                const int* fp = flags + (i - 1) * GN + j;
                int it = 0;
                while (__hip_atomic_load(fp, __ATOMIC_RELAXED,
                                         __HIP_MEMORY_SCOPE_AGENT) < 8) {
                    __builtin_amdgcn_s_sleep(1);
                    if (++it > (1 << 24)) break;   // failsafe, never expected
                }
            }
            if (t == 64 && j > 0) {
                const int* fp = flags + i * GN + (j - 1);
                int it = 0;
                while (__hip_atomic_load(fp, __ATOMIC_RELAXED,
                                         __HIP_MEMORY_SCOPE_AGENT) < 8) {
                    __builtin_amdgcn_s_sleep(1);
                    if (++it > (1 << 24)) break;
                }
            }
            __syncthreads();

            // --- stage Hcat = [h1(i-1,j) | h2(i,j-1) | x(i,j)] as fp16 ---
            // h-parts read with relaxed agent atomics (coherent, no inv).
            for (int e = t; e < BN * 80; e += 256) {
                const int b = e / 80, c4 = e - b * 80;   // c4: 8B chunk (4 fp16)
                u64 v = 0;
                if (c4 < 32) {
                    if (i > 0)
                        v = __hip_atomic_load(
                            (const u64*)(hbuf + ((size_t)((i - 1) * GN + j)) * (BN * KH)
                                         + b * KH + c4 * 4),
                            __ATOMIC_RELAXED, __HIP_MEMORY_SCOPE_AGENT);
                } else if (c4 < 64) {
                    if (j > 0)
                        v = __hip_atomic_load(
                            (const u64*)(hbuf + ((size_t)(i * GN + (j - 1))) * (BN * KH)
                                         + b * KH + c4 * 4),
                            __ATOMIC_RELAXED, __HIP_MEMORY_SCOPE_AGENT);
                } else {
                    v = *(const u64*)(xb + ((size_t)cellidx) * (BN * CN)
                                      + b * CN + (c4 - 64) * 4);
                }
                *(u64*)(&Hc[b * LDSK + c4 * 4]) = v;
            }
            __syncthreads();

            // --- gates[16,128] = Hcat[16,320] @ Wslice^T via MFMA ---
            float4v acc0 = {0.f, 0.f, 0.f, 0.f};
            float4v acc1 = {0.f, 0.f, 0.f, 0.f};
            #pragma unroll
            for (int ks = 0; ks < KTOT / 32; ++ks) {
                const half8 a  = *(const half8*)(&Hc[l15 * LDSK + ks * 32 + l4 * 8]);
                const half8 b0 = *(const half8*)(&Wl[n0 * LDSK + ks * 32 + l4 * 8]);
                const half8 b1 = *(const half8*)(&Wl[n1 * LDSK + ks * 32 + l4 * 8]);
                acc0 = __builtin_amdgcn_mfma_f32_16x16x32_f16(a, b0, acc0, 0, 0, 0);
                acc1 = __builtin_amdgcn_mfma_f32_16x16x32_f16(a, b1, acc1, 0, 0, 0);
            }
            #pragma unroll
            for (int rg = 0; rg < 4; ++rg) {
                const int m = l4 * 4 + rg;
                gb[m * 136 + n0] = acc0[rg] + blds[n0];
                gb[m * 136 + n1] = acc1[rg] + blds[n1];
            }
            __syncthreads();

            // --- pointwise LSTM update: 16 b x 32 units (unit-PAIRED so the
            //     hbuf publish is a u32 and cbuf traffic is u64 atomics) ---
            const int line = (dd == 0) ? j : i;
            const bool hasp = (dd == 0) ? (i > 0) : (j > 0);
            {
                const int uu = (t & 15) * 2;      // unit pair 0,2,..,30
                const int b  = t >> 4;            // batch 0..15
                const float4v gA = *(const float4v*)(&gb[b * 136 + uu * 4]);
                const float4v gB = *(const float4v*)(&gb[b * 136 + uu * 4 + 4]);
                const int huA = ug * 32 + uu;     // huA, huA+1 adjacent
                const size_t cidx = ((size_t)(dd * GN + line) * BN + b) * HN + huA;

                float cpA = 0.f, cpB = 0.f;
                if (hasp) {
                    const u64 cold = __hip_atomic_load(
                        (const u64*)(cbuf + cidx),
                        __ATOMIC_RELAXED, __HIP_MEMORY_SCOPE_AGENT);
                    union { u64 q; float f[2]; } cu; cu.q = cold;
                    cpA = cu.f[0]; cpB = cu.f[1];
                }
                const float giA = sigmoidf_(gA.x), gfA = sigmoidf_(gA.y);
                const float ggA = tanhf(gA.z),    goA = sigmoidf_(gA.w);
                const float giB = sigmoidf_(gB.x), gfB = sigmoidf_(gB.y);
                const float ggB = tanhf(gB.z),    goB = sigmoidf_(gB.w);
                const float cA = gfA * cpA + giA * ggA;
                const float cB = gfB * cpB + giB * ggB;
                union { u64 q; float f[2]; } cn; cn.f[0] = cA; cn.f[1] = cB;
                __hip_atomic_store((u64*)(cbuf + cidx), cn.q,
                                   __ATOMIC_RELAXED, __HIP_MEMORY_SCOPE_AGENT);
                const float hA = goA * tanhf(cA);
                const float hB = goB * tanhf(cB);
                union { unsigned int u; _Float16 f[2]; } hp;
                hp.f[0] = (_Float16)hA; hp.f[1] = (_Float16)hB;
                __hip_atomic_store(
                    (unsigned int*)(hbuf + ((size_t)cellidx) * (BN * KH)
                                    + b * KH + dd * HN + huA),
                    hp.u, __ATOMIC_RELAXED, __HIP_MEMORY_SCOPE_AGENT);
            }
            // every wave drains its coherent stores before the barrier, so
            // t0's flag add (to the same coherence point) orders after them
            asm volatile("s_waitcnt vmcnt(0)" ::: "memory");
            __syncthreads();

            // --- publish: relaxed increment of this cell's flag ---
            if (t == 0)
                __hip_atomic_fetch_add(flags + cellidx, 1,
                                       __ATOMIC_RELAXED, __HIP_MEMORY_SCOPE_AGENT);
        }
    }
}

// ---------------- fallback (round-1 kernel, fp32, launch-per-diagonal) -------
constexpr int KCH = 32;
constexpr int NCH = KTOT / KCH;

__global__ __launch_bounds__(256, 1) void diag_kernel(
    const float* __restrict__ x, const float* __restrict__ Wih,
    const float* __restrict__ Whh, const float* __restrict__ bih,
    const float* __restrict__ bhh, float* __restrict__ out,
    float* __restrict__ cbuf, int d)
{
    __shared__ float HcF[BN][KTOT];
    __shared__ float Wch[KCH][257];
    const int cell = blockIdx.x >> 2;
    const int slice = blockIdx.x & 3;
    const int dd = slice >> 1;
    const int h0 = (slice & 1) * 64;
    const int i0 = (d > GN - 1) ? (d - (GN - 1)) : 0;
    const int i = i0 + cell;
    const int j = d - i;
    const int t = threadIdx.x;
    for (int e = t; e < BN * KTOT; e += 256) {
        const int b = e / KTOT, k = e - b * KTOT;
        float v;
        if (k < HN)      v = (i > 0) ? out[((b * KH + k) * GN + (i - 1)) * GN + j] : 0.f;
        else if (k < KH) v = (j > 0) ? out[((b * KH + k) * GN + i) * GN + (j - 1)] : 0.f;
        else             v = x[((b * CN + (k - KH)) * GN + i) * GN + j];
        HcF[b][k] = v;
    }
    const int h = t & 63, bg = t >> 6;
    const int grow = dd * 4 * HN + bg * HN + h0 + h;
    float acc[4][4];
    #pragma unroll
    for (int qq = 0; qq < 4; ++qq)
        #pragma unroll
        for (int bb = 0; bb < 4; ++bb) acc[qq][bb] = 0.f;
    for (int kb = 0; kb < NCH; ++kb) {
        const int kbase = kb * KCH;
        __syncthreads();
        const float* src = (kbase < KH) ? (Whh + (size_t)grow * KH + kbase)
                                        : (Wih + (size_t)grow * CN + (kbase - KH));
        #pragma unroll
        for (int k4 = 0; k4 < KCH / 4; ++k4) {
            const float4 w = *(const float4*)(src + k4 * 4);
            Wch[k4 * 4 + 0][t] = w.x; Wch[k4 * 4 + 1][t] = w.y;
            Wch[k4 * 4 + 2][t] = w.z; Wch[k4 * 4 + 3][t] = w.w;
        }
        __syncthreads();
        #pragma unroll 8
        for (int kk = 0; kk < KCH; ++kk) {
            const float w0 = Wch[kk][0 * 64 + h], w1 = Wch[kk][1 * 64 + h];
            const float w2 = Wch[kk][2 * 64 + h], w3 = Wch[kk][3 * 64 + h];
            #pragma unroll
            for (int bb = 0; bb < 4; ++bb) {
                const float hv = HcF[bg * 4 + bb][kbase + kk];
                acc[0][bb] = fmaf(w0, hv, acc[0][bb]);
                acc[1][bb] = fmaf(w1, hv, acc[1][bb]);
                acc[2][bb] = fmaf(w2, hv, acc[2][bb]);
                acc[3][bb] = fmaf(w3, hv, acc[3][bb]);
            }
        }
    }
    const int hu = h0 + h;
    float bias[4];
    #pragma unroll
    for (int qq = 0; qq < 4; ++qq) {
        const int gidx = dd * 4 * HN + qq * HN + hu;
        bias[qq] = bih[gidx] + bhh[gidx];
    }
    float* cptr = (dd == 0) ? (cbuf + (size_t)j * BN * HN)
                            : (cbuf + (size_t)GN * BN * HN + (size_t)i * BN * HN);
    const bool has_prev = (dd == 0) ? (i > 0) : (j > 0);
    #pragma unroll
    for (int bb = 0; bb < 4; ++bb) {
        const int b = bg * 4 + bb;
        const float gi = sigmoidf_(acc[0][bb] + bias[0]);
        const float gf = sigmoidf_(acc[1][bb] + bias[1]);
        const float gg = tanhf(acc[2][bb] + bias[2]);
        const float go = sigmoidf_(acc[3][bb] + bias[3]);
        const float cp = has_prev ? cptr[b * HN + hu] : 0.f;
        const float c = gf * cp + gi * gg;
        cptr[b * HN + hu] = c;
        out[((b * KH + dd * HN + hu) * GN + i) * GN + j] = go * tanhf(c);
    }
}

} // anonymous namespace

extern "C" void kernel_launch(void* const* d_in, const int* in_sizes, int n_in,
                              void* d_out, int out_size, void* d_ws, size_t ws_size,
                              hipStream_t stream) {
    const float* x   = (const float*)d_in[0];
    const float* Wih = (const float*)d_in[1];
    const float* Whh = (const float*)d_in[2];
    const float* bih = (const float*)d_in[3];
    const float* bhh = (const float*)d_in[4];
    float* out = (float*)d_out;

    const size_t XB_BYTES = (size_t)GN * GN * BN * CN * 2;        // 8 MB
    const size_t HB_BYTES = (size_t)GN * GN * BN * KH * 2;        // 8 MB
    const size_t CB_BYTES = (size_t)2 * GN * BN * HN * 4;         // 1 MB
    const size_t FL_BYTES = (size_t)GN * GN * 4;                  // 16 KB
    const size_t NEED = XB_BYTES + HB_BYTES + CB_BYTES + FL_BYTES;

    if (ws_size >= NEED) {
        _Float16* xbp  = (_Float16*)d_ws;
        _Float16* hbuf = (_Float16*)((char*)d_ws + XB_BYTES);
        float*    cbuf = (float*)((char*)d_ws + XB_BYTES + HB_BYTES);
        int*      flags = (int*)((char*)d_ws + XB_BYTES + HB_BYTES + CB_BYTES);

        hipMemsetAsync(flags, 0, FL_BYTES, stream);
        hipLaunchKernelGGL(xconv_kernel, dim3(BN * GN), dim3(256), 0, stream, x, xbp);

        void* args[] = { (void*)&xbp, (void*)&Wih, (void*)&Whh, (void*)&bih,
                         (void*)&bhh, (void*)&hbuf, (void*)&cbuf, (void*)&flags };
        hipLaunchCooperativeKernel((const void*)grid_lstm_persist,
                                   dim3(256), dim3(256), args, 0, stream);

        hipLaunchKernelGGL(out_kernel, dim3(BN * GN), dim3(256), 0, stream, hbuf, out);
    } else {
        float* cbuf = (float*)d_ws;
        for (int d = 0; d < 2 * GN - 1; ++d) {
            const int i0 = (d > GN - 1) ? (d - (GN - 1)) : 0;
            const int i1 = (d < GN - 1) ? d : (GN - 1);
            const int nc = i1 - i0 + 1;
            hipLaunchKernelGGL(diag_kernel, dim3(nc * 4), dim3(256), 0, stream,
                               x, Wih, Whh, bih, bhh, out, cbuf, d);
        }
    }
}